// Round 12
// baseline (134.743 us; speedup 1.0000x reference)
//
#include <hip/hip_runtime.h>
#include <math.h>

typedef unsigned long long u64;

#define H 2048
#define W 2048
#define NWR 64          // word-rows (H/32)
#define TILE 128        // output cols per K2 block
#define HALO 32         // LDS halo; reg window d<=8, LDS d<=32, then global walk
#define LW 192          // TILE + 2*HALO
#define LSTRIDE 193     // odd stride: row index -> distinct bank
#define DCLAMP 2900     // > max possible distance; f <= 8.41e6 exact in fp32
#define NTHR 256
#define NBLK2 1024      // k2 grid size (16 x 64)

// ---------------------------------------------------------------------------
// Far-walks on the background bitmask (rare; out-of-line keeps hot loop small)
// ---------------------------------------------------------------------------
__device__ __attribute__((noinline)) int vfar_up(const unsigned* rmask, int col, int r, int ks) {
    for (int kk = ks - 2; kk >= 0; --kk) {
        unsigned w = rmask[kk * W + col];
        if (w) return r - (kk * 32 + (31 - __clz(w)));
    }
    return DCLAMP;
}
__device__ __attribute__((noinline)) int vfar_dn(const unsigned* rmask, int col, int r, int ks) {
    for (int kk = ks + 2; kk < NWR; ++kk) {
        unsigned w = rmask[kk * W + col];
        if (w) return (kk * 32 + (__ffs(w) - 1)) - r;
    }
    return DCLAMP;
}

// exact f at arbitrary (r, col) straight from the bitmask (never-taken fallback)
__device__ __attribute__((noinline)) float f_from_mask(const unsigned* rmask, int col, int r) {
    int kw = r >> 5, b = r & 31;
    unsigned wm1 = (kw > 0)       ? rmask[(kw - 1) * W + col] : 0u;
    unsigned w0  =                  rmask[kw * W + col];
    unsigned wp1 = (kw < NWR - 1) ? rmask[(kw + 1) * W + col] : 0u;
    if ((w0 >> b) & 1u) return 0.0f;
    u64 A  = (u64)wm1 | ((u64)w0 << 32);
    u64 Bv = (u64)w0  | ((u64)wp1 << 32);
    int p = 32 + b;
    u64 Am = A & ((1ull << p) - 1ull);
    int da = Am ? (p - (63 - __clzll(Am))) : vfar_up(rmask, col, r, kw);
    u64 Bm = Bv >> (b + 1);
    int db = Bm ? __ffsll(Bm) : vfar_dn(rmask, col, r, kw);
    int d1 = min(min(da, db), DCLAMP);
    return (float)d1 * (float)d1;
}

// ---------------------------------------------------------------------------
// K1: pack background bits; one thread per mask word; coalesced.
// Thread 0 zero-inits maxp and the barrier counter (stream-ordered before K2).
// ---------------------------------------------------------------------------
__global__ void k1_pack(const float* __restrict__ img, unsigned* __restrict__ rmask,
                        unsigned int* __restrict__ maxp, unsigned int* __restrict__ done) {
    int gid = blockIdx.x * NTHR + threadIdx.x;
    if (gid == 0) { *maxp = 0u; *done = 0u; }
    int col = gid & (W - 1);
    int kw  = gid >> 11;
    unsigned w = 0;
#pragma unroll
    for (int i = 0; i < 32; ++i)
        w |= (img[(size_t)(kw * 32 + i) * W + col] <= 0.5f ? 1u : 0u) << i;
    rmask[kw * W + col] = w;
}

// ---------------------------------------------------------------------------
// K2 (fused EDT + normalize): block = (128-col tile, 32-row word-row).
// Phase 1: decode f = d1^2 per column into LDS from 3 mask words.
// Phase 2: register sliding window row pass (exact; rare LDS d<=32 extension;
//          never-taken exact global walk) -> res in regs.
// Phase 3: stage res into LDS; block max -> atomicMax(maxp).
// Barrier: thread 0 release-adds the done counter and spins (acquire, agent
//          scope) until all 1024 blocks arrived. Only 4 bytes cross blocks —
//          no bulk L2 flush needed (this is why it's cheap vs grid.sync).
//          Residency guaranteed: 24.7 KB LDS (6 blocks/CU) and
//          __launch_bounds__(256,5) (>=5 blocks/CU) -> capacity >= 1280 > 1024.
// Phase 4: normalize from LDS with the global max; coalesced int4 store
//          (uint8 semantics: trunc(d/m*255)).
// ---------------------------------------------------------------------------
__global__ void __launch_bounds__(NTHR, 5)
k2_fused(const unsigned* __restrict__ rmask, int* __restrict__ out,
         unsigned int* __restrict__ maxp, unsigned int* __restrict__ done) {
    __shared__ float ftile[32][LSTRIDE];   // 24.7 KB
    __shared__ float smax[5];
    const int tid = threadIdx.x;
    const int c0 = blockIdx.x * TILE;
    const int ks = blockIdx.y;
    const int rbase = ks * 32;

    // ---- Phase 1: decode one column into LDS
    if (tid < LW) {
        int gc = c0 - HALO + tid;
        if (gc >= 0 && gc < W) {
            unsigned wm1 = (ks > 0)       ? rmask[(ks - 1) * W + gc] : 0u;
            unsigned w0  =                  rmask[ks * W + gc];
            unsigned wp1 = (ks < NWR - 1) ? rmask[(ks + 1) * W + gc] : 0u;
            u64 A  = (u64)wm1 | ((u64)w0 << 32);
            u64 Bv = (u64)w0  | ((u64)wp1 << 32);
#pragma unroll
            for (int i = 0; i < 32; ++i) {
                int p = 32 + i;
                u64 Am = A & ((1ull << p) - 1ull);
                int da = Am ? (p - (63 - __clzll(Am))) : vfar_up(rmask, gc, rbase + i, ks);
                u64 Bm = Bv >> (i + 1);
                int db = Bm ? __ffsll(Bm) : vfar_dn(rmask, gc, rbase + i, ks);
                int d1 = min(min(da, db), DCLAMP);
                float fd = (float)d1;
                ftile[i][tid] = ((w0 >> i) & 1u) ? 0.0f : fd * fd;
            }
        } else {
#pragma unroll
            for (int i = 0; i < 32; ++i)
                ftile[i][tid] = 1e9f;   // pad: cost >= 1e9 never wins
        }
    }
    __syncthreads();

    // ---- Phase 2: register sliding window (exact)
    const int i  = tid & 31;        // row within tile
    const int p  = tid >> 5;        // 16-col strip
    const int lc = HALO + p * 16;   // LDS col of first output
    float reg[32];                  // f for LDS cols lc-8 .. lc+23
#pragma unroll
    for (int k = 0; k < 32; ++k)
        reg[k] = ftile[i][lc - 8 + k];

    float res[16];
    float lmax = 0.0f;
#pragma unroll
    for (int m = 0; m < 16; ++m) {
        float best = reg[m + 8];
#pragma unroll
        for (int d = 1; d <= 8; ++d) {
            float q = (float)(d * d);
            best = fminf(best, reg[m + 8 - d] + q);
            best = fminf(best, reg[m + 8 + d] + q);
        }
        if (__builtin_expect(81.0f < best, 0)) {
            for (int d = 9; d <= HALO && (float)(d * d) < best; ++d) {
                float q = (float)(d * d);
                best = fminf(best, ftile[i][lc + m - d] + q);
                best = fminf(best, ftile[i][lc + m + d] + q);
            }
            if ((float)((HALO + 1) * (HALO + 1)) < best) {
                // exact global fallback (never taken for random 50% mask)
                int r = rbase + i, jj = c0 + p * 16 + m;
                for (int d = HALO + 1; d < W && (float)(d * d) < best; ++d) {
                    float q = (float)(d * d);
                    int jm = jj - d, jp = jj + d;
                    if (jm >= 0) best = fminf(best, f_from_mask(rmask, jm, r) + q);
                    if (jp < W)  best = fminf(best, f_from_mask(rmask, jp, r) + q);
                }
            }
        }
        float rr = sqrtf(best);
        res[m] = rr;
        lmax = fmaxf(lmax, rr);
    }

    // ---- Phase 3: stage res to LDS; block max -> device atomic
    __syncthreads();   // all ftile reads done
#pragma unroll
    for (int m = 0; m < 16; ++m)
        ftile[i][p * 16 + m] = res[m];

    for (int o = 32; o > 0; o >>= 1) lmax = fmaxf(lmax, __shfl_down(lmax, o, 64));
    if ((tid & 63) == 0) smax[1 + (tid >> 6)] = lmax;
    __syncthreads();

    // ---- Barrier on 4-byte counter (only maxp crosses blocks)
    if (tid == 0) {
        float bm = fmaxf(fmaxf(smax[1], smax[2]), fmaxf(smax[3], smax[4]));
        atomicMax(maxp, __float_as_uint(bm));   // device-scope, values >= 0
        __hip_atomic_fetch_add(done, 1u, __ATOMIC_ACQ_REL, __HIP_MEMORY_SCOPE_AGENT);
        while (__hip_atomic_load(done, __ATOMIC_ACQUIRE, __HIP_MEMORY_SCOPE_AGENT) < NBLK2)
            __builtin_amdgcn_s_sleep(8);
        smax[0] = __uint_as_float(__hip_atomic_load(maxp, __ATOMIC_ACQUIRE,
                                                    __HIP_MEMORY_SCOPE_AGENT));
    }
    __syncthreads();

    // ---- Phase 4: normalize from LDS, coalesced int4 store
    float m = smax[0];
    float scale = (m > 0.0f) ? 1.0f / m : 0.0f;
#pragma unroll
    for (int q = 0; q < 4; ++q) {
        int r  = (tid >> 5) + 8 * q;      // 0..31
        int c4 = (tid & 31) * 4;
        int o[4];
#pragma unroll
        for (int k = 0; k < 4; ++k) {
            float dv = ftile[r][c4 + k];
            float v = (m > 0.0f) ? (dv * scale * 255.0f) : dv;  // d/m*255 order-equiv
            v = fminf(fmaxf(v, 0.0f), 255.0f);
            o[k] = (int)v;                                      // trunc, like astype(uint8)
        }
        *(int4*)(out + (size_t)(rbase + r) * W + c0 + c4) = make_int4(o[0], o[1], o[2], o[3]);
    }
}

extern "C" void kernel_launch(void* const* d_in, const int* in_sizes, int n_in,
                              void* d_out, int out_size, void* d_ws, size_t ws_size,
                              hipStream_t stream) {
    const float* img = (const float*)d_in[0];
    int* out = (int*)d_out;

    // ws: rmask 512 KB | maxp 4 B | done 4 B
    unsigned* rmask = (unsigned*)d_ws;
    unsigned int* maxp = (unsigned int*)((char*)d_ws + (size_t)NWR * W * 4);
    unsigned int* done = maxp + 1;

    k1_pack <<<dim3(NWR * W / NTHR), dim3(NTHR), 0, stream>>>(img, rmask, maxp, done);
    k2_fused<<<dim3(W / TILE, NWR), dim3(NTHR), 0, stream>>>(rmask, out, maxp, done);
}

// Round 13
// 122.656 us; speedup vs baseline: 1.0985x; 1.0985x over previous
//
#include <hip/hip_runtime.h>
#include <math.h>

typedef unsigned long long u64;

#define H 2048
#define W 2048
#define NWR 64          // word-rows (H/32)
#define TILE 128        // output cols per K2 block
#define HALO 32         // LDS halo; reg window d<=8, LDS d<=32, then global walk
#define LW 192          // TILE + 2*HALO
#define LSTRIDE 193     // odd stride: row index -> distinct bank
#define DCLAMP 2900     // > max possible distance; f <= 8.41e6 exact in fp32
#define NTHR 256
#define NBLK2 1024      // k2 grid size (16 x 64)

// ---------------------------------------------------------------------------
// Far-walks on the background bitmask (rare; out-of-line keeps hot loop small)
// ---------------------------------------------------------------------------
__device__ __attribute__((noinline)) int vfar_up(const unsigned* rmask, int col, int r, int ks) {
    for (int kk = ks - 2; kk >= 0; --kk) {
        unsigned w = rmask[kk * W + col];
        if (w) return r - (kk * 32 + (31 - __clz(w)));
    }
    return DCLAMP;
}
__device__ __attribute__((noinline)) int vfar_dn(const unsigned* rmask, int col, int r, int ks) {
    for (int kk = ks + 2; kk < NWR; ++kk) {
        unsigned w = rmask[kk * W + col];
        if (w) return (kk * 32 + (__ffs(w) - 1)) - r;
    }
    return DCLAMP;
}

// exact f at arbitrary (r, col) straight from the bitmask (never-taken fallback)
__device__ __attribute__((noinline)) float f_from_mask(const unsigned* rmask, int col, int r) {
    int kw = r >> 5, b = r & 31;
    unsigned wm1 = (kw > 0)       ? rmask[(kw - 1) * W + col] : 0u;
    unsigned w0  =                  rmask[kw * W + col];
    unsigned wp1 = (kw < NWR - 1) ? rmask[(kw + 1) * W + col] : 0u;
    if ((w0 >> b) & 1u) return 0.0f;
    u64 A  = (u64)wm1 | ((u64)w0 << 32);
    u64 Bv = (u64)w0  | ((u64)wp1 << 32);
    int p = 32 + b;
    u64 Am = A & ((1ull << p) - 1ull);
    int da = Am ? (p - (63 - __clzll(Am))) : vfar_up(rmask, col, r, kw);
    u64 Bm = Bv >> (b + 1);
    int db = Bm ? __ffsll(Bm) : vfar_dn(rmask, col, r, kw);
    int d1 = min(min(da, db), DCLAMP);
    return (float)d1 * (float)d1;
}

// ---------------------------------------------------------------------------
// K1: pack background bits; one thread per mask word; coalesced.
// Thread 0 zero-inits maxp and the barrier counter (stream-ordered before K2).
// ---------------------------------------------------------------------------
__global__ void k1_pack(const float* __restrict__ img, unsigned* __restrict__ rmask,
                        unsigned int* __restrict__ maxp, unsigned int* __restrict__ done) {
    int gid = blockIdx.x * NTHR + threadIdx.x;
    if (gid == 0) { *maxp = 0u; *done = 0u; }
    int col = gid & (W - 1);
    int kw  = gid >> 11;
    unsigned w = 0;
#pragma unroll
    for (int i = 0; i < 32; ++i)
        w |= (img[(size_t)(kw * 32 + i) * W + col] <= 0.5f ? 1u : 0u) << i;
    rmask[kw * W + col] = w;
}

// ---------------------------------------------------------------------------
// K2 (fused EDT + normalize). Barrier design: the ONLY cross-block datum is
// maxp (an atomic — always coherent at its home). So: atomicMax; fetch_add
// RELEASE (drains the atomicMax to the coherence point first); spin on
// RELAXED loads (no per-iteration cache invalidate — the R12 mistake: ACQUIRE
// spin at agent scope invalidates L2 every poll, evicting rmask under the
// still-computing blocks); final maxp read RELAXED. Residency guaranteed:
// 24.7 KB LDS -> 6 blocks/CU and launch_bounds(256,5) -> capacity 1280>1024.
// ---------------------------------------------------------------------------
__global__ void __launch_bounds__(NTHR, 5)
k2_fused(const unsigned* __restrict__ rmask, int* __restrict__ out,
         unsigned int* __restrict__ maxp, unsigned int* __restrict__ done) {
    __shared__ float ftile[32][LSTRIDE];   // 24.7 KB
    __shared__ float smax[5];
    const int tid = threadIdx.x;
    const int c0 = blockIdx.x * TILE;
    const int ks = blockIdx.y;
    const int rbase = ks * 32;

    // ---- Phase 1: decode one column of f = d1^2 into LDS
    if (tid < LW) {
        int gc = c0 - HALO + tid;
        if (gc >= 0 && gc < W) {
            unsigned wm1 = (ks > 0)       ? rmask[(ks - 1) * W + gc] : 0u;
            unsigned w0  =                  rmask[ks * W + gc];
            unsigned wp1 = (ks < NWR - 1) ? rmask[(ks + 1) * W + gc] : 0u;
            u64 A  = (u64)wm1 | ((u64)w0 << 32);
            u64 Bv = (u64)w0  | ((u64)wp1 << 32);
#pragma unroll
            for (int i = 0; i < 32; ++i) {
                int p = 32 + i;
                u64 Am = A & ((1ull << p) - 1ull);
                int da = Am ? (p - (63 - __clzll(Am))) : vfar_up(rmask, gc, rbase + i, ks);
                u64 Bm = Bv >> (i + 1);
                int db = Bm ? __ffsll(Bm) : vfar_dn(rmask, gc, rbase + i, ks);
                int d1 = min(min(da, db), DCLAMP);
                float fd = (float)d1;
                ftile[i][tid] = ((w0 >> i) & 1u) ? 0.0f : fd * fd;
            }
        } else {
#pragma unroll
            for (int i = 0; i < 32; ++i)
                ftile[i][tid] = 1e9f;   // pad: cost >= 1e9 never wins
        }
    }
    __syncthreads();

    // ---- Phase 2: register sliding window (exact)
    const int i  = tid & 31;        // row within tile
    const int p  = tid >> 5;        // 16-col strip
    const int lc = HALO + p * 16;   // LDS col of first output
    float reg[32];                  // f for LDS cols lc-8 .. lc+23
#pragma unroll
    for (int k = 0; k < 32; ++k)
        reg[k] = ftile[i][lc - 8 + k];

    float res[16];
    float lmax = 0.0f;
#pragma unroll
    for (int m = 0; m < 16; ++m) {
        float best = reg[m + 8];
#pragma unroll
        for (int d = 1; d <= 8; ++d) {
            float q = (float)(d * d);
            best = fminf(best, reg[m + 8 - d] + q);
            best = fminf(best, reg[m + 8 + d] + q);
        }
        if (__builtin_expect(81.0f < best, 0)) {
            for (int d = 9; d <= HALO && (float)(d * d) < best; ++d) {
                float q = (float)(d * d);
                best = fminf(best, ftile[i][lc + m - d] + q);
                best = fminf(best, ftile[i][lc + m + d] + q);
            }
            if ((float)((HALO + 1) * (HALO + 1)) < best) {
                // exact global fallback (never taken for random 50% mask)
                int r = rbase + i, jj = c0 + p * 16 + m;
                for (int d = HALO + 1; d < W && (float)(d * d) < best; ++d) {
                    float q = (float)(d * d);
                    int jm = jj - d, jp = jj + d;
                    if (jm >= 0) best = fminf(best, f_from_mask(rmask, jm, r) + q);
                    if (jp < W)  best = fminf(best, f_from_mask(rmask, jp, r) + q);
                }
            }
        }
        float rr = sqrtf(best);
        res[m] = rr;
        lmax = fmaxf(lmax, rr);
    }

    // ---- Phase 3: stage res to LDS; block max -> device atomic
    __syncthreads();   // all ftile reads done
#pragma unroll
    for (int m = 0; m < 16; ++m)
        ftile[i][p * 16 + m] = res[m];

    for (int o = 32; o > 0; o >>= 1) lmax = fmaxf(lmax, __shfl_down(lmax, o, 64));
    if ((tid & 63) == 0) smax[1 + (tid >> 6)] = lmax;
    __syncthreads();

    // ---- 4-byte barrier: RELEASE count-in, RELAXED spin, RELAXED readback
    if (tid == 0) {
        float bm = fmaxf(fmaxf(smax[1], smax[2]), fmaxf(smax[3], smax[4]));
        atomicMax(maxp, __float_as_uint(bm));   // device-scope, values >= 0
        __hip_atomic_fetch_add(done, 1u, __ATOMIC_RELEASE, __HIP_MEMORY_SCOPE_AGENT);
        while (__hip_atomic_load(done, __ATOMIC_RELAXED, __HIP_MEMORY_SCOPE_AGENT) < NBLK2)
            __builtin_amdgcn_s_sleep(16);
        smax[0] = __uint_as_float(__hip_atomic_load(maxp, __ATOMIC_RELAXED,
                                                    __HIP_MEMORY_SCOPE_AGENT));
    }
    __syncthreads();

    // ---- Phase 4: normalize from LDS, coalesced int4 store
    float m = smax[0];
    float scale = (m > 0.0f) ? 1.0f / m : 0.0f;
#pragma unroll
    for (int q = 0; q < 4; ++q) {
        int r  = (tid >> 5) + 8 * q;      // 0..31
        int c4 = (tid & 31) * 4;
        int o[4];
#pragma unroll
        for (int k = 0; k < 4; ++k) {
            float dv = ftile[r][c4 + k];
            float v = (m > 0.0f) ? (dv * scale * 255.0f) : dv;  // d/m*255 order-equiv
            v = fminf(fmaxf(v, 0.0f), 255.0f);
            o[k] = (int)v;                                      // trunc, like astype(uint8)
        }
        *(int4*)(out + (size_t)(rbase + r) * W + c0 + c4) = make_int4(o[0], o[1], o[2], o[3]);
    }
}

extern "C" void kernel_launch(void* const* d_in, const int* in_sizes, int n_in,
                              void* d_out, int out_size, void* d_ws, size_t ws_size,
                              hipStream_t stream) {
    const float* img = (const float*)d_in[0];
    int* out = (int*)d_out;

    // ws: rmask 512 KB | maxp (own line) | done (separate cache line, +128 B)
    unsigned* rmask = (unsigned*)d_ws;
    unsigned int* maxp = (unsigned int*)((char*)d_ws + (size_t)NWR * W * 4);
    unsigned int* done = (unsigned int*)((char*)d_ws + (size_t)NWR * W * 4 + 128);

    k1_pack <<<dim3(NWR * W / NTHR), dim3(NTHR), 0, stream>>>(img, rmask, maxp, done);
    k2_fused<<<dim3(W / TILE, NWR), dim3(NTHR), 0, stream>>>(rmask, out, maxp, done);
}

// Round 14
// 88.496 us; speedup vs baseline: 1.5226x; 1.3860x over previous
//
#include <hip/hip_runtime.h>
#include <math.h>

typedef unsigned long long u64;

#define H 2048
#define W 2048
#define NWR 64          // word-rows (H/32)
#define TILE 128        // output cols per K2 block
#define HALO 32         // LDS halo; reg window d<=8, LDS d<=32, then global walk
#define LW 192          // TILE + 2*HALO
#define LSTRIDE 193     // odd stride: row index -> distinct bank
#define DCLAMP 2900     // > max possible distance; f <= 8.41e6 exact in fp32
#define NTHR 256
#define NBLK2 1024      // k2 grid (16 x 64)

// ---------------------------------------------------------------------------
// Far-walks on the background bitmask (rare; out-of-line keeps hot loop small)
// ---------------------------------------------------------------------------
__device__ __attribute__((noinline)) int vfar_up(const unsigned* rmask, int col, int r, int ks) {
    for (int kk = ks - 2; kk >= 0; --kk) {
        unsigned w = rmask[kk * W + col];
        if (w) return r - (kk * 32 + (31 - __clz(w)));
    }
    return DCLAMP;
}
__device__ __attribute__((noinline)) int vfar_dn(const unsigned* rmask, int col, int r, int ks) {
    for (int kk = ks + 2; kk < NWR; ++kk) {
        unsigned w = rmask[kk * W + col];
        if (w) return (kk * 32 + (__ffs(w) - 1)) - r;
    }
    return DCLAMP;
}

// exact f at arbitrary (r, col) straight from the bitmask (never-taken fallback)
__device__ __attribute__((noinline)) float f_from_mask(const unsigned* rmask, int col, int r) {
    int kw = r >> 5, b = r & 31;
    unsigned wm1 = (kw > 0)       ? rmask[(kw - 1) * W + col] : 0u;
    unsigned w0  =                  rmask[kw * W + col];
    unsigned wp1 = (kw < NWR - 1) ? rmask[(kw + 1) * W + col] : 0u;
    if ((w0 >> b) & 1u) return 0.0f;
    u64 A  = (u64)wm1 | ((u64)w0 << 32);
    u64 Bv = (u64)w0  | ((u64)wp1 << 32);
    int p = 32 + b;
    u64 Am = A & ((1ull << p) - 1ull);
    int da = Am ? (p - (63 - __clzll(Am))) : vfar_up(rmask, col, r, kw);
    u64 Bm = Bv >> (b + 1);
    int db = Bm ? __ffsll(Bm) : vfar_dn(rmask, col, r, kw);
    int d1 = min(min(da, db), DCLAMP);
    return (float)d1 * (float)d1;
}

// ---------------------------------------------------------------------------
// K1: pack background bits; one thread per mask word; fully coalesced.
// ---------------------------------------------------------------------------
__global__ void k1_pack(const float* __restrict__ img, unsigned* __restrict__ rmask) {
    int gid = blockIdx.x * NTHR + threadIdx.x;
    int col = gid & (W - 1);
    int kw  = gid >> 11;
    unsigned w = 0;
#pragma unroll
    for (int i = 0; i < 32; ++i)
        w |= (img[(size_t)(kw * 32 + i) * W + col] <= 0.5f ? 1u : 0u) << i;
    rmask[kw * W + col] = w;
}

// ---------------------------------------------------------------------------
// K2: block = (128-col tile, 32-row word-row). Decode f = d1^2 per column
// into LDS from 3 mask words; register sliding-window exact row pass
// (rare LDS d<=32 extension; never-taken exact global walk); coalesced fp32
// sqrt store. Block max -> ONE PLAIN STORE to partial[blockid]. NO ATOMICS —
// 1024 same-address device atomics were the hidden ~35 µs serial tail
// (~30 ns each under cross-XCD contention) in every prior round.
// ---------------------------------------------------------------------------
__global__ void __launch_bounds__(NTHR)
k2_edt(const unsigned* __restrict__ rmask, float* __restrict__ dist,
       float* __restrict__ partial) {
    __shared__ float ftile[32][LSTRIDE];   // 24.7 KB
    __shared__ float smax[4];
    const int tid = threadIdx.x;
    const int c0 = blockIdx.x * TILE;
    const int ks = blockIdx.y;
    const int rbase = ks * 32;

    // ---- Phase 1: decode one column of f = d1^2 into LDS
    if (tid < LW) {
        int gc = c0 - HALO + tid;
        if (gc >= 0 && gc < W) {
            unsigned wm1 = (ks > 0)       ? rmask[(ks - 1) * W + gc] : 0u;
            unsigned w0  =                  rmask[ks * W + gc];
            unsigned wp1 = (ks < NWR - 1) ? rmask[(ks + 1) * W + gc] : 0u;
            u64 A  = (u64)wm1 | ((u64)w0 << 32);
            u64 Bv = (u64)w0  | ((u64)wp1 << 32);
#pragma unroll
            for (int i = 0; i < 32; ++i) {
                int p = 32 + i;
                u64 Am = A & ((1ull << p) - 1ull);
                int da = Am ? (p - (63 - __clzll(Am))) : vfar_up(rmask, gc, rbase + i, ks);
                u64 Bm = Bv >> (i + 1);
                int db = Bm ? __ffsll(Bm) : vfar_dn(rmask, gc, rbase + i, ks);
                int d1 = min(min(da, db), DCLAMP);
                float fd = (float)d1;
                ftile[i][tid] = ((w0 >> i) & 1u) ? 0.0f : fd * fd;
            }
        } else {
#pragma unroll
            for (int i = 0; i < 32; ++i)
                ftile[i][tid] = 1e9f;   // pad: cost >= 1e9 never wins
        }
    }
    __syncthreads();

    // ---- Phase 2: register sliding window (exact)
    const int i  = tid & 31;        // row within tile
    const int p  = tid >> 5;        // 16-col strip
    const int lc = HALO + p * 16;   // LDS col of first output
    float reg[32];                  // f for LDS cols lc-8 .. lc+23
#pragma unroll
    for (int k = 0; k < 32; ++k)
        reg[k] = ftile[i][lc - 8 + k];

    float res[16];
    float lmax = 0.0f;
#pragma unroll
    for (int m = 0; m < 16; ++m) {
        float best = reg[m + 8];
#pragma unroll
        for (int d = 1; d <= 8; ++d) {
            float q = (float)(d * d);
            best = fminf(best, reg[m + 8 - d] + q);
            best = fminf(best, reg[m + 8 + d] + q);
        }
        if (__builtin_expect(81.0f < best, 0)) {
            for (int d = 9; d <= HALO && (float)(d * d) < best; ++d) {
                float q = (float)(d * d);
                best = fminf(best, ftile[i][lc + m - d] + q);
                best = fminf(best, ftile[i][lc + m + d] + q);
            }
            if ((float)((HALO + 1) * (HALO + 1)) < best) {
                // exact global fallback (never taken for random 50% mask)
                int r = rbase + i, jj = c0 + p * 16 + m;
                for (int d = HALO + 1; d < W && (float)(d * d) < best; ++d) {
                    float q = (float)(d * d);
                    int jm = jj - d, jp = jj + d;
                    if (jm >= 0) best = fminf(best, f_from_mask(rmask, jm, r) + q);
                    if (jp < W)  best = fminf(best, f_from_mask(rmask, jp, r) + q);
                }
            }
        }
        float rr = sqrtf(best);
        res[m] = rr;
        lmax = fmaxf(lmax, rr);
    }

    // ---- Phase 3: stage res to LDS; coalesced float4 store
    __syncthreads();   // all ftile reads done
#pragma unroll
    for (int m = 0; m < 16; ++m)
        ftile[i][p * 16 + m] = res[m];
    __syncthreads();
#pragma unroll
    for (int q = 0; q < 4; ++q) {
        int r  = (tid >> 5) + 8 * q;      // 0..31
        int c4 = (tid & 31) * 4;
        float4 v = make_float4(ftile[r][c4], ftile[r][c4 + 1],
                               ftile[r][c4 + 2], ftile[r][c4 + 3]);
        *(float4*)(dist + (size_t)(rbase + r) * W + c0 + c4) = v;
    }

    // ---- block max -> plain store (kernel boundary is the barrier)
    for (int o = 32; o > 0; o >>= 1) lmax = fmaxf(lmax, __shfl_down(lmax, o, 64));
    if ((tid & 63) == 0) smax[tid >> 6] = lmax;
    __syncthreads();
    if (tid == 0)
        partial[ks * (W / TILE) + blockIdx.x] =
            fmaxf(fmaxf(smax[0], smax[1]), fmaxf(smax[2], smax[3]));
}

// ---------------------------------------------------------------------------
// K3: each block redundantly reduces the 1024 partials (4 L2-hot loads/thread
// + shuffle — ~1 µs aggregate, no atomics), then normalizes its 16384-pixel
// slice in place: float4 -> int4, uint8 semantics trunc(d * (1/m) * 255)
// (same numerics as R13, which matched exactly).
// ---------------------------------------------------------------------------
__global__ void __launch_bounds__(NTHR)
k3_norm(int* __restrict__ out, const float* __restrict__ partial) {
    __shared__ float sm[4];
    const int tid = threadIdx.x;
    float v = 0.0f;
#pragma unroll
    for (int k = 0; k < 4; ++k)
        v = fmaxf(v, partial[tid * 4 + k]);
    for (int o = 32; o > 0; o >>= 1) v = fmaxf(v, __shfl_down(v, o, 64));
    if ((tid & 63) == 0) sm[tid >> 6] = v;
    __syncthreads();
    float m = fmaxf(fmaxf(sm[0], sm[1]), fmaxf(sm[2], sm[3]));
    float scale = (m > 0.0f) ? 1.0f / m : 0.0f;

    size_t base = (size_t)blockIdx.x * 16384;
#pragma unroll 4
    for (int t = 0; t < 16; ++t) {
        size_t idx = base + ((size_t)t * NTHR + tid) * 4;
        float4 dv = *(const float4*)((const float*)out + idx);
        float r[4] = {dv.x, dv.y, dv.z, dv.w};
        int o[4];
#pragma unroll
        for (int k = 0; k < 4; ++k) {
            float vv = (m > 0.0f) ? (r[k] * scale * 255.0f) : r[k];
            vv = fminf(fmaxf(vv, 0.0f), 255.0f);
            o[k] = (int)vv;                   // trunc, like astype(uint8)
        }
        *(int4*)(out + idx) = make_int4(o[0], o[1], o[2], o[3]);
    }
}

extern "C" void kernel_launch(void* const* d_in, const int* in_sizes, int n_in,
                              void* d_out, int out_size, void* d_ws, size_t ws_size,
                              hipStream_t stream) {
    const float* img = (const float*)d_in[0];
    int* out = (int*)d_out;

    // ws: rmask 512 KB | partial 4 KB (written by every k2 block; no init needed)
    unsigned* rmask = (unsigned*)d_ws;
    float* partial  = (float*)((char*)d_ws + (size_t)NWR * W * 4);

    k1_pack<<<dim3(NWR * W / NTHR), dim3(NTHR), 0, stream>>>(img, rmask);
    k2_edt <<<dim3(W / TILE, NWR), dim3(NTHR), 0, stream>>>(rmask, (float*)out, partial);
    k3_norm<<<dim3(H * W / 16384), dim3(NTHR), 0, stream>>>(out, partial);
}

// Round 15
// 85.473 us; speedup vs baseline: 1.5764x; 1.0354x over previous
//
#include <hip/hip_runtime.h>
#include <math.h>

typedef unsigned long long u64;

#define H 2048
#define W 2048
#define NWR 64          // word-rows (H/32)
#define TILE 128        // output cols per K2 block
#define HALO 32         // LDS halo; reg window d<=8, LDS d<=32, then global walk
#define LW 192          // TILE + 2*HALO
#define LSTRIDE 193     // odd stride: row index -> distinct bank
#define DCLAMP 2900     // > max possible distance; f <= 8.41e6 exact in fp32
#define NTHR 256
#define NBLK2 1024      // k2 grid (16 x 64) == residency capacity, see barrier note

// ---------------------------------------------------------------------------
// Far-walks on the background bitmask (rare; out-of-line keeps hot loop small)
// ---------------------------------------------------------------------------
__device__ __attribute__((noinline)) int vfar_up(const unsigned* rmask, int col, int r, int ks) {
    for (int kk = ks - 2; kk >= 0; --kk) {
        unsigned w = rmask[kk * W + col];
        if (w) return r - (kk * 32 + (31 - __clz(w)));
    }
    return DCLAMP;
}
__device__ __attribute__((noinline)) int vfar_dn(const unsigned* rmask, int col, int r, int ks) {
    for (int kk = ks + 2; kk < NWR; ++kk) {
        unsigned w = rmask[kk * W + col];
        if (w) return (kk * 32 + (__ffs(w) - 1)) - r;
    }
    return DCLAMP;
}

// exact f at arbitrary (r, col) straight from the bitmask (never-taken fallback)
__device__ __attribute__((noinline)) float f_from_mask(const unsigned* rmask, int col, int r) {
    int kw = r >> 5, b = r & 31;
    unsigned wm1 = (kw > 0)       ? rmask[(kw - 1) * W + col] : 0u;
    unsigned w0  =                  rmask[kw * W + col];
    unsigned wp1 = (kw < NWR - 1) ? rmask[(kw + 1) * W + col] : 0u;
    if ((w0 >> b) & 1u) return 0.0f;
    u64 A  = (u64)wm1 | ((u64)w0 << 32);
    u64 Bv = (u64)w0  | ((u64)wp1 << 32);
    int p = 32 + b;
    u64 Am = A & ((1ull << p) - 1ull);
    int da = Am ? (p - (63 - __clzll(Am))) : vfar_up(rmask, col, r, kw);
    u64 Bm = Bv >> (b + 1);
    int db = Bm ? __ffsll(Bm) : vfar_dn(rmask, col, r, kw);
    int d1 = min(min(da, db), DCLAMP);
    return (float)d1 * (float)d1;
}

// ---------------------------------------------------------------------------
// K1: pack background bits (coalesced) + zero-init the barrier cells.
// ---------------------------------------------------------------------------
__global__ void k1_pack(const float* __restrict__ img, unsigned* __restrict__ rmask,
                        unsigned int* __restrict__ valid, unsigned int* __restrict__ flag) {
    int gid = blockIdx.x * NTHR + threadIdx.x;
    if (gid < NBLK2) valid[gid] = 0u;
    if (gid == NBLK2) *flag = 0u;
    int col = gid & (W - 1);
    int kw  = gid >> 11;
    unsigned w = 0;
#pragma unroll
    for (int i = 0; i < 32; ++i)
        w |= (img[(size_t)(kw * 32 + i) * W + col] <= 0.5f ? 1u : 0u) << i;
    rmask[kw * W + col] = w;
}

// ---------------------------------------------------------------------------
// K2 (fused EDT + max + normalize). Barrier has ZERO same-address RMWs (the
// R12/R13 lesson: 1024 same-address device atomics serialize at ~30ns each):
//   each block release-STOREs valid[blk] = bits(max)+1  (distinct addrs);
//   block 0 polls all 1024 with relaxed atomic loads (monotone), reduces,
//   release-stores flag = bits(globalmax)+1; others spin flag with relaxed
//   LOADS (reads don't serialize). Results live in LDS across the wait.
// Residency (deadlock-free): LDS 24.7 KB -> 6 blocks/CU; launch_bounds(256,4)
// caps VGPR at 128 -> >=4 blocks/CU; capacity >= 1024 = grid, dispatcher
// places every block (in-order fill of any free CU).
// ---------------------------------------------------------------------------
__global__ void __launch_bounds__(NTHR, 4)
k2_fused(const unsigned* __restrict__ rmask, int* __restrict__ out,
         unsigned int* __restrict__ valid, unsigned int* __restrict__ flag) {
    __shared__ float ftile[32][LSTRIDE];   // 24.7 KB
    __shared__ float smax[5];
    const int tid = threadIdx.x;
    const int c0 = blockIdx.x * TILE;
    const int ks = blockIdx.y;
    const int rbase = ks * 32;
    const int bid = ks * (W / TILE) + blockIdx.x;

    // ---- Phase 1: decode one column of f = d1^2 into LDS
    if (tid < LW) {
        int gc = c0 - HALO + tid;
        if (gc >= 0 && gc < W) {
            unsigned wm1 = (ks > 0)       ? rmask[(ks - 1) * W + gc] : 0u;
            unsigned w0  =                  rmask[ks * W + gc];
            unsigned wp1 = (ks < NWR - 1) ? rmask[(ks + 1) * W + gc] : 0u;
            u64 A  = (u64)wm1 | ((u64)w0 << 32);
            u64 Bv = (u64)w0  | ((u64)wp1 << 32);
#pragma unroll
            for (int i = 0; i < 32; ++i) {
                int p = 32 + i;
                u64 Am = A & ((1ull << p) - 1ull);
                int da = Am ? (p - (63 - __clzll(Am))) : vfar_up(rmask, gc, rbase + i, ks);
                u64 Bm = Bv >> (i + 1);
                int db = Bm ? __ffsll(Bm) : vfar_dn(rmask, gc, rbase + i, ks);
                int d1 = min(min(da, db), DCLAMP);
                float fd = (float)d1;
                ftile[i][tid] = ((w0 >> i) & 1u) ? 0.0f : fd * fd;
            }
        } else {
#pragma unroll
            for (int i = 0; i < 32; ++i)
                ftile[i][tid] = 1e9f;   // pad: cost >= 1e9 never wins
        }
    }
    __syncthreads();

    // ---- Phase 2: register sliding window (exact)
    const int i  = tid & 31;        // row within tile
    const int p  = tid >> 5;        // 16-col strip
    const int lc = HALO + p * 16;   // LDS col of first output
    float reg[32];                  // f for LDS cols lc-8 .. lc+23
#pragma unroll
    for (int k = 0; k < 32; ++k)
        reg[k] = ftile[i][lc - 8 + k];

    float res[16];
    float lmax = 0.0f;
#pragma unroll
    for (int m = 0; m < 16; ++m) {
        float best = reg[m + 8];
#pragma unroll
        for (int d = 1; d <= 8; ++d) {
            float q = (float)(d * d);
            best = fminf(best, reg[m + 8 - d] + q);
            best = fminf(best, reg[m + 8 + d] + q);
        }
        if (__builtin_expect(81.0f < best, 0)) {
            for (int d = 9; d <= HALO && (float)(d * d) < best; ++d) {
                float q = (float)(d * d);
                best = fminf(best, ftile[i][lc + m - d] + q);
                best = fminf(best, ftile[i][lc + m + d] + q);
            }
            if ((float)((HALO + 1) * (HALO + 1)) < best) {
                // exact global fallback (never taken for random 50% mask)
                int r = rbase + i, jj = c0 + p * 16 + m;
                for (int d = HALO + 1; d < W && (float)(d * d) < best; ++d) {
                    float q = (float)(d * d);
                    int jm = jj - d, jp = jj + d;
                    if (jm >= 0) best = fminf(best, f_from_mask(rmask, jm, r) + q);
                    if (jp < W)  best = fminf(best, f_from_mask(rmask, jp, r) + q);
                }
            }
        }
        float rr = sqrtf(best);
        res[m] = rr;
        lmax = fmaxf(lmax, rr);
    }

    // ---- Phase 3: stage res to LDS (stays there across the barrier)
    __syncthreads();   // all ftile reads done
#pragma unroll
    for (int m = 0; m < 16; ++m)
        ftile[i][p * 16 + m] = res[m];

    for (int o = 32; o > 0; o >>= 1) lmax = fmaxf(lmax, __shfl_down(lmax, o, 64));
    if ((tid & 63) == 0) smax[1 + (tid >> 6)] = lmax;
    __syncthreads();

    // ---- Store/poll barrier (no RMWs anywhere)
    if (tid == 0) {
        float bm = fmaxf(fmaxf(smax[1], smax[2]), fmaxf(smax[3], smax[4]));
        // bits of non-negative float are order-preserving; +1 makes 0.0 distinguishable from "not ready"
        __hip_atomic_store(&valid[bid], __float_as_uint(bm) + 1u,
                           __ATOMIC_RELEASE, __HIP_MEMORY_SCOPE_AGENT);
    }
    if (bid == 0) {
        // reducer block: poll all 1024 valid cells (monotone 0 -> nonzero)
        unsigned mv = 0;
#pragma unroll
        for (int k = 0; k < NBLK2 / NTHR; ++k) {
            unsigned v;
            while ((v = __hip_atomic_load(&valid[tid * (NBLK2 / NTHR) + k],
                                          __ATOMIC_RELAXED, __HIP_MEMORY_SCOPE_AGENT)) == 0u)
                __builtin_amdgcn_s_sleep(4);
            mv = max(mv, v);
        }
        float v = __uint_as_float(mv - 1u);
        for (int o = 32; o > 0; o >>= 1) v = fmaxf(v, __shfl_down(v, o, 64));
        if ((tid & 63) == 0) smax[1 + (tid >> 6)] = v;
        __syncthreads();
        if (tid == 0) {
            float gm = fmaxf(fmaxf(smax[1], smax[2]), fmaxf(smax[3], smax[4]));
            smax[0] = gm;
            __hip_atomic_store(flag, __float_as_uint(gm) + 1u,
                               __ATOMIC_RELEASE, __HIP_MEMORY_SCOPE_AGENT);
        }
    } else if (tid == 0) {
        unsigned fv;
        while ((fv = __hip_atomic_load(flag, __ATOMIC_RELAXED,
                                       __HIP_MEMORY_SCOPE_AGENT)) == 0u)
            __builtin_amdgcn_s_sleep(8);
        smax[0] = __uint_as_float(fv - 1u);
    }
    __syncthreads();

    // ---- Phase 4: normalize from LDS, coalesced int4 store (uint8 semantics)
    float m = smax[0];
    float scale = (m > 0.0f) ? 1.0f / m : 0.0f;
#pragma unroll
    for (int q = 0; q < 4; ++q) {
        int r  = (tid >> 5) + 8 * q;      // 0..31
        int c4 = (tid & 31) * 4;
        int o[4];
#pragma unroll
        for (int k = 0; k < 4; ++k) {
            float dv = ftile[r][c4 + k];
            float v = (m > 0.0f) ? (dv * scale * 255.0f) : dv;
            v = fminf(fmaxf(v, 0.0f), 255.0f);
            o[k] = (int)v;                // trunc, like astype(uint8)
        }
        *(int4*)(out + (size_t)(rbase + r) * W + c0 + c4) = make_int4(o[0], o[1], o[2], o[3]);
    }
}

extern "C" void kernel_launch(void* const* d_in, const int* in_sizes, int n_in,
                              void* d_out, int out_size, void* d_ws, size_t ws_size,
                              hipStream_t stream) {
    const float* img = (const float*)d_in[0];
    int* out = (int*)d_out;

    // ws: rmask 512 KB | valid[1024] 4 KB | flag (own cache line)
    unsigned* rmask = (unsigned*)d_ws;
    unsigned int* valid = (unsigned int*)((char*)d_ws + (size_t)NWR * W * 4);
    unsigned int* flag  = (unsigned int*)((char*)d_ws + (size_t)NWR * W * 4 + 4096 + 128);

    k1_pack <<<dim3(NWR * W / NTHR), dim3(NTHR), 0, stream>>>(img, rmask, valid, flag);
    k2_fused<<<dim3(W / TILE, NWR), dim3(NTHR), 0, stream>>>(rmask, out, valid, flag);
}